// Round 2
// baseline (228.077 us; speedup 1.0000x reference)
//
#include <hip/hip_runtime.h>
#include <hip/hip_bf16.h>

// Problem constants (fixed by setup_inputs)
#define B   8
#define T   2048
#define C   256      // channels; 64 float4
#define L   32       // query rows / label count
#define DQ  512
#define NW  2017     // T - window_size + 1
#define NK  8        // num_chunks
#define CIC 4        // window/num_chunks
#define WT  32       // w-tile per block in out kernel
#define SROWS (WT + (NK-1)*CIC)   // 60 S4 rows per tile

// ---------------- Kernel 1: enc1/enc2 = query @ W{1,2} + b{1,2} ----------------
// grid (8 lgroups, 8 b), block 256 (=c). 4 query rows per block.
__global__ __launch_bounds__(256) void enc_kernel(
    const float* __restrict__ query, const float* __restrict__ W1,
    const float* __restrict__ b1, const float* __restrict__ W2,
    const float* __restrict__ b2, float* __restrict__ enc1,
    float* __restrict__ enc2) {
  const int b = blockIdx.y, lg = blockIdx.x;   // 4 l per block
  const int c = threadIdx.x;
  __shared__ float qs[4 * DQ];
  const float* qbase = query + ((size_t)b * L + lg * 4) * DQ;
  for (int i = c; i < 4 * DQ; i += 256) qs[i] = qbase[i];
  __syncthreads();
  float a1[4] = {0.f, 0.f, 0.f, 0.f};
  float a2[4] = {0.f, 0.f, 0.f, 0.f};
  for (int d = 0; d < DQ; ++d) {
    const float w1 = W1[d * C + c];
    const float w2 = W2[d * C + c];
#pragma unroll
    for (int j = 0; j < 4; ++j) {
      a1[j] = fmaf(qs[j * DQ + d], w1, a1[j]);
      a2[j] = fmaf(qs[j * DQ + d], w2, a2[j]);
    }
  }
  const float bb1 = b1[c], bb2 = b2[c];
#pragma unroll
  for (int j = 0; j < 4; ++j) {
    const size_t o = ((size_t)b * L + lg * 4 + j) * C + c;
    enc1[o] = a1[j] + bb1;
    enc2[o] = a2[j] + bb2;
  }
}

// ---------------- Kernel 2: clip_labels = argmax_l (vis . enc1) ----------------
// grid (32 t-tiles, 8 b), block 256. 64 t per block; 4 threads per t split c.
__global__ __launch_bounds__(256) void label_kernel(
    const float* __restrict__ vis, const float* __restrict__ enc1,
    int* __restrict__ labels) {
  const int b = blockIdx.y;
  const int t0 = blockIdx.x * 64;
  const int tid = threadIdx.x;
  const int tl = tid & 63;    // local t
  const int part = tid >> 6;  // c-quarter (wave-uniform)
  __shared__ float4 e1[L * (C / 4)];      // 32KB: enc1[b]
  __shared__ float pacc[64][4 * L + 1];   // +1 pad breaks 64-way bank conflict
  const float4* esrc = (const float4*)(enc1 + (size_t)b * L * C);
  for (int i = tid; i < L * (C / 4); i += 256) e1[i] = esrc[i];
  __syncthreads();

  const int t = t0 + tl;
  const float4* vrow = (const float4*)(vis + ((size_t)b * T + t) * C);
  float acc[L];
#pragma unroll
  for (int l = 0; l < L; ++l) acc[l] = 0.f;
  const int c4b = part * 16;
  for (int j = 0; j < 16; ++j) {
    const float4 v = vrow[c4b + j];
#pragma unroll
    for (int l = 0; l < L; ++l) {
      const float4 e = e1[l * 64 + c4b + j];   // LDS broadcast
      acc[l] = fmaf(v.x, e.x, fmaf(v.y, e.y, fmaf(v.z, e.z, fmaf(v.w, e.w, acc[l]))));
    }
  }
#pragma unroll
  for (int l = 0; l < L; ++l) pacc[tl][part * L + l] = acc[l];
  __syncthreads();
  if (tid < 64) {
    float bv = -INFINITY;
    int bi = 0;
#pragma unroll
    for (int l = 0; l < L; ++l) {
      const float s = pacc[tid][l] + pacc[tid][L + l] + pacc[tid][2 * L + l] +
                      pacc[tid][3 * L + l];
      if (s > bv) { bv = s; bi = l; }   // first max wins, matches jnp.argmax
    }
    labels[(size_t)b * T + t0 + tid] = bi;
  }
}

// ---------------- Kernel 3: fused majority-vote + pooled * gathered ----------------
// grid (ceil(NW/WT)=64, 8 b), block 256. LDS: 60 S4 rows (60KB) + 60 labels.
__global__ __launch_bounds__(256) void out_kernel(
    const float* __restrict__ vis, const float* __restrict__ enc2,
    const int* __restrict__ labels, float* __restrict__ out) {
  const int b = blockIdx.y;
  const int w0 = blockIdx.x * WT;
  const int tid = threadIdx.x;
  const int lane = tid & 63;
  const int part = tid >> 6;            // wave id, wave-uniform
  __shared__ float4 S4[SROWS * (C / 4)];  // 60 x 1KB, pre-scaled by 0.25
  __shared__ int slbl[SROWS];

  // Phase 1: running-window 4-row sums. 4 waves x 15 s-rows each.
  // S4[s] = mean(vis rows w0+s .. w0+s+3). At iteration s registers hold
  // rows w0+s..w0+s+3; refill for s+1 is row w0+s+4 (NOT +5 — R1 bugfix).
  const float4* vb = (const float4*)(vis + (size_t)b * T * C);
  const int s_begin = part * (SROWS / 4);
  {
    const int tcur = w0 + s_begin;
#define VROW(tt) vb[(size_t)((tt) > (T - 1) ? (T - 1) : (tt)) * (C / 4) + lane]
    float4 r0 = VROW(tcur), r1 = VROW(tcur + 1), r2 = VROW(tcur + 2), r3 = VROW(tcur + 3);
    for (int s = s_begin; s < s_begin + SROWS / 4; ++s) {
      float4 sum;
      sum.x = (r0.x + r1.x + r2.x + r3.x) * 0.25f;
      sum.y = (r0.y + r1.y + r2.y + r3.y) * 0.25f;
      sum.z = (r0.z + r1.z + r2.z + r3.z) * 0.25f;
      sum.w = (r0.w + r1.w + r2.w + r3.w) * 0.25f;
      S4[s * (C / 4) + lane] = sum;
      r0 = r1; r1 = r2; r2 = r3; r3 = VROW(w0 + s + 4);
    }
#undef VROW
  }

  // Phase 2: majority vote over 4 labels, tie -> smallest label (== argmax of counts)
  if (tid < SROWS) {
    const int* lb = labels + (size_t)b * T;
    const int t = w0 + tid;
#define LCL(tt) lb[(tt) > (T - 1) ? (T - 1) : (tt)]
    const int l0 = LCL(t), l1 = LCL(t + 1), l2 = LCL(t + 2), l3 = LCL(t + 3);
#undef LCL
    const int c0 = 1 + (l0 == l1) + (l0 == l2) + (l0 == l3);
    const int c1 = 1 + (l1 == l0) + (l1 == l2) + (l1 == l3);
    const int c2 = 1 + (l2 == l0) + (l2 == l1) + (l2 == l3);
    const int c3 = 1 + (l3 == l0) + (l3 == l1) + (l3 == l2);
    int best = l0, bc = c0;
    if (c1 > bc || (c1 == bc && l1 < best)) { best = l1; bc = c1; }
    if (c2 > bc || (c2 == bc && l2 < best)) { best = l2; bc = c2; }
    if (c3 > bc || (c3 == bc && l3 < best)) { best = l3; bc = c3; }
    slbl[tid] = best;
  }
  __syncthreads();

  // Phase 3: 256 output rows (32 w x 8 k), one per wave-iteration
  const float4* e2b = (const float4*)(enc2 + (size_t)b * L * C);
  float4* outp = (float4*)out;
  for (int i = part; i < WT * NK; i += 4) {   // wave-uniform trip
    const int w = i >> 3, k = i & 7;
    const int ww = w0 + w;
    if (ww >= NW) continue;                   // wave-uniform branch
    const int s = w + CIC * k;
    const int lbl = slbl[s];                  // LDS broadcast
    const float4 e = e2b[lbl * (C / 4) + lane];
    const float4 sv = S4[s * (C / 4) + lane];
    float4 o;
    o.x = e.x * sv.x; o.y = e.y * sv.y; o.z = e.z * sv.z; o.w = e.w * sv.w;
    outp[(((size_t)b * NW + ww) * NK + k) * (C / 4) + lane] = o;
  }
}

extern "C" void kernel_launch(void* const* d_in, const int* in_sizes, int n_in,
                              void* d_out, int out_size, void* d_ws, size_t ws_size,
                              hipStream_t stream) {
  const float* vis   = (const float*)d_in[0];
  const float* query = (const float*)d_in[1];
  const float* W1    = (const float*)d_in[2];
  const float* b1    = (const float*)d_in[3];
  const float* W2    = (const float*)d_in[4];
  const float* b2    = (const float*)d_in[5];
  float* out = (float*)d_out;

  // Workspace: enc1 (64K f), enc2 (64K f), labels (16K int) = 576 KB
  float* enc1 = (float*)d_ws;
  float* enc2 = enc1 + (size_t)B * L * C;
  int* labels = (int*)(enc2 + (size_t)B * L * C);

  enc_kernel<<<dim3(L / 4, B), 256, 0, stream>>>(query, W1, b1, W2, b2, enc1, enc2);
  label_kernel<<<dim3(T / 64, B), 256, 0, stream>>>(vis, enc1, labels);
  out_kernel<<<dim3((NW + WT - 1) / WT, B), 256, 0, stream>>>(vis, enc2, labels, out);
}

// Round 3
// 217.888 us; speedup vs baseline: 1.0468x; 1.0468x over previous
//
#include <hip/hip_runtime.h>
#include <hip/hip_bf16.h>

// Problem constants (fixed by setup_inputs)
#define B   8
#define T   2048
#define C   256      // channels; 64 float4
#define L   32       // query rows / label count
#define DQ  512
#define NW  2017     // T - window_size + 1
#define NK  8        // num_chunks
#define CIC 4        // window/num_chunks
#define WT  32       // w-tile per block in out kernel
#define SROWS (WT + (NK-1)*CIC)   // 60 S4 rows per tile

// ---------------- Kernel 1: enc1/enc2 = query @ W{1,2} + b{1,2} ----------------
// grid (8 lgroups, 8 b), block (256 c, 4 d-quarters). LDS reduce over quarters.
__global__ __launch_bounds__(1024) void enc_kernel(
    const float* __restrict__ query, const float* __restrict__ W1,
    const float* __restrict__ b1, const float* __restrict__ W2,
    const float* __restrict__ b2, float* __restrict__ enc1,
    float* __restrict__ enc2) {
  const int b = blockIdx.y, lg = blockIdx.x;   // 4 l per block
  const int c = threadIdx.x;                   // 0..255
  const int q = threadIdx.y;                   // 0..3 d-quarter
  __shared__ float qs[4 * DQ];                 // 8 KB
  __shared__ float red[2][4][4][256];          // [enc][q][j][c] 32 KB
  const float* qbase = query + ((size_t)b * L + lg * 4) * DQ;
  for (int i = q * 256 + c; i < 4 * DQ; i += 1024) qs[i] = qbase[i];
  __syncthreads();
  float a1[4] = {0.f, 0.f, 0.f, 0.f};
  float a2[4] = {0.f, 0.f, 0.f, 0.f};
  const int d0 = q * (DQ / 4);
#pragma unroll 4
  for (int dd = 0; dd < DQ / 4; ++dd) {
    const int d = d0 + dd;
    const float w1 = W1[d * C + c];
    const float w2 = W2[d * C + c];
#pragma unroll
    for (int j = 0; j < 4; ++j) {
      a1[j] = fmaf(qs[j * DQ + d], w1, a1[j]);
      a2[j] = fmaf(qs[j * DQ + d], w2, a2[j]);
    }
  }
#pragma unroll
  for (int j = 0; j < 4; ++j) {
    red[0][q][j][c] = a1[j];
    red[1][q][j][c] = a2[j];
  }
  __syncthreads();
  for (int o = q * 256 + c; o < 2048; o += 1024) {
    const int e = o >> 10;         // 0..1 (enc1/enc2)
    const int j = (o >> 8) & 3;    // row within lgroup
    const int cc = o & 255;
    const float v = red[e][0][j][cc] + red[e][1][j][cc] +
                    red[e][2][j][cc] + red[e][3][j][cc];
    const size_t off = ((size_t)b * L + lg * 4 + j) * C + cc;
    if (e == 0) enc1[off] = v + b1[cc];
    else        enc2[off] = v + b2[cc];
  }
}

// ---------------- Kernel 2: clip_labels = argmax_l (vis . enc1) ----------------
// grid (T/32, 8 b), block 256. 32 t per block; 8 threads per t split c.
// LDS 65 KB -> 2 blocks/CU -> 8 waves/CU.
__global__ __launch_bounds__(256) void label_kernel(
    const float* __restrict__ vis, const float* __restrict__ enc1,
    int* __restrict__ labels) {
  const int b = blockIdx.y;
  const int t0 = blockIdx.x * 32;
  const int tid = threadIdx.x;
  const int tl = tid & 31;    // local t
  const int part = tid >> 5;  // c-eighth (half-wave-uniform)
  __shared__ float4 e1[L * (C / 4)];      // 32 KB: enc1[b]
  __shared__ float pacc[32][8 * L + 1];   // 32.9 KB; +1 keeps banks conflict-free
  const float4* esrc = (const float4*)(enc1 + (size_t)b * L * C);
  for (int i = tid; i < L * (C / 4); i += 256) e1[i] = esrc[i];
  __syncthreads();

  const float4* vrow = (const float4*)(vis + ((size_t)b * T + t0 + tl) * C);
  float acc[L];
#pragma unroll
  for (int l = 0; l < L; ++l) acc[l] = 0.f;
  const int c4b = part * 8;
#pragma unroll
  for (int j = 0; j < 8; ++j) {
    const float4 v = vrow[c4b + j];
#pragma unroll
    for (int l = 0; l < L; ++l) {
      const float4 e = e1[l * 64 + c4b + j];   // 2-address LDS broadcast (free)
      acc[l] = fmaf(v.x, e.x, fmaf(v.y, e.y, fmaf(v.z, e.z, fmaf(v.w, e.w, acc[l]))));
    }
  }
#pragma unroll
  for (int l = 0; l < L; ++l) pacc[tl][part * L + l] = acc[l];
  __syncthreads();
  if (tid < 32) {
    float bv = -INFINITY;
    int bi = 0;
#pragma unroll
    for (int l = 0; l < L; ++l) {
      float s = 0.f;
#pragma unroll
      for (int p = 0; p < 8; ++p) s += pacc[tid][p * L + l];
      if (s > bv) { bv = s; bi = l; }   // first max wins, matches jnp.argmax
    }
    labels[(size_t)b * T + t0 + tid] = bi;
  }
}

// ---------------- Kernel 3: fused majority-vote + pooled * gathered ----------------
// grid (ceil(NW/WT)=64, 8 b), block 256. LDS: 60 S4 rows (60KB) + 60 labels.
__global__ __launch_bounds__(256) void out_kernel(
    const float* __restrict__ vis, const float* __restrict__ enc2,
    const int* __restrict__ labels, float* __restrict__ out) {
  const int b = blockIdx.y;
  const int w0 = blockIdx.x * WT;
  const int tid = threadIdx.x;
  const int lane = tid & 63;
  const int part = tid >> 6;            // wave id, wave-uniform
  __shared__ float4 S4[SROWS * (C / 4)];  // 60 x 1KB, pre-scaled by 0.25
  __shared__ int slbl[SROWS];

  // Phase 1: S4[s] = mean(vis rows w0+s .. w0+s+3). Each wave owns 15 s-rows;
  // loads its 18 raw rows as INDEPENDENT loads (one vmcnt drain, no serial
  // rotation chain — R3 restructure).
  const float4* vb = (const float4*)(vis + (size_t)b * T * C);
  {
    const int s_begin = part * (SROWS / 4);   // 15 per wave
    float4 r[18];
#pragma unroll
    for (int j = 0; j < 18; ++j) {
      int t = w0 + s_begin + j;
      t = t > (T - 1) ? (T - 1) : t;          // clamp; clamped rows never used
      r[j] = vb[(size_t)t * (C / 4) + lane];
    }
#pragma unroll
    for (int s = 0; s < SROWS / 4; ++s) {
      float4 sum;
      sum.x = (r[s].x + r[s + 1].x + r[s + 2].x + r[s + 3].x) * 0.25f;
      sum.y = (r[s].y + r[s + 1].y + r[s + 2].y + r[s + 3].y) * 0.25f;
      sum.z = (r[s].z + r[s + 1].z + r[s + 2].z + r[s + 3].z) * 0.25f;
      sum.w = (r[s].w + r[s + 1].w + r[s + 2].w + r[s + 3].w) * 0.25f;
      S4[(s_begin + s) * (C / 4) + lane] = sum;
    }
  }

  // Phase 2: majority vote over 4 labels, tie -> smallest label (== argmax of counts)
  if (tid < SROWS) {
    const int* lb = labels + (size_t)b * T;
    const int t = w0 + tid;
#define LCL(tt) lb[(tt) > (T - 1) ? (T - 1) : (tt)]
    const int l0 = LCL(t), l1 = LCL(t + 1), l2 = LCL(t + 2), l3 = LCL(t + 3);
#undef LCL
    const int c0 = 1 + (l0 == l1) + (l0 == l2) + (l0 == l3);
    const int c1 = 1 + (l1 == l0) + (l1 == l2) + (l1 == l3);
    const int c2 = 1 + (l2 == l0) + (l2 == l1) + (l2 == l3);
    const int c3 = 1 + (l3 == l0) + (l3 == l1) + (l3 == l2);
    int best = l0, bc = c0;
    if (c1 > bc || (c1 == bc && l1 < best)) { best = l1; bc = c1; }
    if (c2 > bc || (c2 == bc && l2 < best)) { best = l2; bc = c2; }
    if (c3 > bc || (c3 == bc && l3 < best)) { best = l3; bc = c3; }
    slbl[tid] = best;
  }
  __syncthreads();

  // Phase 3: wave `part` owns chunk indices k in {part, part+4}; w sweeps the
  // tile. Constant-shape loops so the compiler can unroll + pipeline.
  const float4* e2b = (const float4*)(enc2 + (size_t)b * L * C);
  float4* outp = (float4*)out;
  const int wlim = (NW - w0) < WT ? (NW - w0) : WT;
#pragma unroll
  for (int kk = 0; kk < 2; ++kk) {
    const int k = part + kk * 4;
#pragma unroll 4
    for (int w = 0; w < wlim; ++w) {
      const int s = w + CIC * k;
      const int lbl = slbl[s];                  // LDS broadcast
      const float4 e = e2b[lbl * (C / 4) + lane];
      const float4 sv = S4[s * (C / 4) + lane];
      float4 o;
      o.x = e.x * sv.x; o.y = e.y * sv.y; o.z = e.z * sv.z; o.w = e.w * sv.w;
      outp[(((size_t)b * NW + w0 + w) * NK + k) * (C / 4) + lane] = o;
    }
  }
}

extern "C" void kernel_launch(void* const* d_in, const int* in_sizes, int n_in,
                              void* d_out, int out_size, void* d_ws, size_t ws_size,
                              hipStream_t stream) {
  const float* vis   = (const float*)d_in[0];
  const float* query = (const float*)d_in[1];
  const float* W1    = (const float*)d_in[2];
  const float* b1    = (const float*)d_in[3];
  const float* W2    = (const float*)d_in[4];
  const float* b2    = (const float*)d_in[5];
  float* out = (float*)d_out;

  // Workspace: enc1 (64K f), enc2 (64K f), labels (16K int) = 576 KB
  float* enc1 = (float*)d_ws;
  float* enc2 = enc1 + (size_t)B * L * C;
  int* labels = (int*)(enc2 + (size_t)B * L * C);

  enc_kernel<<<dim3(L / 4, B), dim3(256, 4), 0, stream>>>(query, W1, b1, W2, b2, enc1, enc2);
  label_kernel<<<dim3(T / 32, B), 256, 0, stream>>>(vis, enc1, labels);
  out_kernel<<<dim3((NW + WT - 1) / WT, B), 256, 0, stream>>>(vis, enc2, labels, out);
}